// Round 1
// baseline (415.375 us; speedup 1.0000x reference)
//
#include <hip/hip_runtime.h>

constexpr int Bsz = 2;
constexpr int Ssz = 2048;
constexpr int Hid = 2048;
constexpr int NHd = 16;
constexpr int Hd  = 128;
constexpr int Mrows = Bsz * Ssz;                 // 4096
constexpr float kScale = 0.08838834764831845f;   // Hd^-0.5

typedef __bf16 bf16;
typedef __bf16 bf16x8 __attribute__((ext_vector_type(8)));
typedef __bf16 bf16x4 __attribute__((ext_vector_type(4)));
typedef float  f32x4  __attribute__((ext_vector_type(4)));

__device__ __forceinline__ void gload_lds16(const bf16* g, bf16* l) {
  __builtin_amdgcn_global_load_lds((const __attribute__((address_space(1))) void*)g,
                                   (__attribute__((address_space(3))) void*)l, 16, 0, 0);
}

// ---------------- f32 -> bf16 bulk convert (4 elems/thread) ----------------
__global__ void k_cvt(const float* __restrict__ in, bf16* __restrict__ out, int n4) {
  int i = blockIdx.x * blockDim.x + threadIdx.x;
  if (i >= n4) return;
  float4 v = ((const float4*)in)[i];
  bf16x4 o = { (bf16)v.x, (bf16)v.y, (bf16)v.z, (bf16)v.w };
  ((bf16x4*)out)[i] = o;
}

// ------------- transpose 4 weights [K][N] f32 -> [N][K] bf16 ---------------
__global__ void k_wtrans(const float* __restrict__ w0, const float* __restrict__ w1,
                         const float* __restrict__ w2, const float* __restrict__ w3,
                         bf16* __restrict__ out) {
  __shared__ float tile[32][33];
  int z = blockIdx.z;
  const float* w = (z == 0) ? w0 : (z == 1) ? w1 : (z == 2) ? w2 : w3;
  bf16* o = out + (size_t)z * Hid * Hid;
  int n0 = blockIdx.x * 32, k0 = blockIdx.y * 32;
  int tx = threadIdx.x, ty = threadIdx.y;
#pragma unroll
  for (int i = 0; i < 4; i++)
    tile[ty + i * 8][tx] = w[(size_t)(k0 + ty + i * 8) * Hid + n0 + tx];
  __syncthreads();
#pragma unroll
  for (int i = 0; i < 4; i++)
    o[(size_t)(n0 + ty + i * 8) * Hid + k0 + tx] = (bf16)tile[tx][ty + i * 8];
}

// ---------------- m97-structure bf16 GEMM, 128x128 tile, BK=32 -------------
// MODE 0: C = A@W^T + bias -> scatter bf16 into [b][h][s][hd] (z picks q/k/v)
// MODE 1: C = A@W^T -> f32 row-major d_out
template <int MODE>
__global__ __launch_bounds__(256, 2) void k_gemm(const bf16* __restrict__ A,
                                                 const bf16* __restrict__ Bt,
                                                 const float* __restrict__ biasq,
                                                 const float* __restrict__ biask,
                                                 const float* __restrict__ biasv,
                                                 bf16* __restrict__ Qo, bf16* __restrict__ Ko,
                                                 bf16* __restrict__ Vo, float* __restrict__ Fo) {
  constexpr int KK = Hid;
  const int z = blockIdx.z;
  const bf16* Bw = Bt + (size_t)z * Hid * Hid;
  const int m0 = blockIdx.y * 128, n0 = blockIdx.x * 128;
  __shared__ bf16 As[128][32];
  __shared__ bf16 Bs[128][32];
  const int tid = threadIdx.x;
  const int lane = tid & 63, wid = tid >> 6;
  const int wr = wid >> 1, wcc = wid & 1;
  const int srow = lane >> 2, scol = (lane & 3) * 8;
  const bf16* Ag = A + (size_t)(m0 + wid * 16 + srow) * KK + scol;
  const bf16* Bg = Bw + (size_t)(n0 + wid * 16 + srow) * KK + scol;
  const int frow = lane & 15, fk8 = (lane >> 4) * 8;
  f32x4 acc[4][4] = {};
  for (int k0 = 0; k0 < KK; k0 += 32) {
    __syncthreads();
    gload_lds16(Ag + k0, &As[wid * 16][0]);
    gload_lds16(Ag + (size_t)64 * KK + k0, &As[64 + wid * 16][0]);
    gload_lds16(Bg + k0, &Bs[wid * 16][0]);
    gload_lds16(Bg + (size_t)64 * KK + k0, &Bs[64 + wid * 16][0]);
    __syncthreads();
    bf16x8 af[4], bfr[4];
#pragma unroll
    for (int i = 0; i < 4; i++) af[i] = *(const bf16x8*)&As[wr * 64 + i * 16 + frow][fk8];
#pragma unroll
    for (int i = 0; i < 4; i++) bfr[i] = *(const bf16x8*)&Bs[wcc * 64 + i * 16 + frow][fk8];
#pragma unroll
    for (int mi = 0; mi < 4; mi++)
#pragma unroll
      for (int ni = 0; ni < 4; ni++)
        acc[mi][ni] = __builtin_amdgcn_mfma_f32_16x16x32_bf16(af[mi], bfr[ni], acc[mi][ni], 0, 0, 0);
  }
  if (MODE == 0) {
    const float* bias = (z == 0) ? biasq : (z == 1) ? biask : biasv;
    bf16* o = (z == 0) ? Qo : (z == 1) ? Ko : Vo;
#pragma unroll
    for (int ni = 0; ni < 4; ni++) {
      const int col = n0 + wcc * 64 + ni * 16 + frow;
      const float bb_ = bias[col];
      const int h = col >> 7, hd = col & (Hd - 1);
#pragma unroll
      for (int mi = 0; mi < 4; mi++) {
#pragma unroll
        for (int r = 0; r < 4; r++) {
          const int row = m0 + wr * 64 + mi * 16 + (lane >> 4) * 4 + r;
          const int bb = row >> 11, ss = row & (Ssz - 1);
          o[(((size_t)bb * NHd + h) * Ssz + ss) * Hd + hd] = (bf16)(acc[mi][ni][r] + bb_);
        }
      }
    }
  } else {
#pragma unroll
    for (int mi = 0; mi < 4; mi++)
#pragma unroll
      for (int ni = 0; ni < 4; ni++) {
        const int col = n0 + wcc * 64 + ni * 16 + frow;
#pragma unroll
        for (int r = 0; r < 4; r++) {
          const int row = m0 + wr * 64 + mi * 16 + (lane >> 4) * 4 + r;
          Fo[(size_t)row * Hid + col] = acc[mi][ni][r];
        }
      }
  }
}

// ---------------- RoPE (neox) on Q and K in place --------------------------
__global__ void k_rope(bf16* __restrict__ Q, bf16* __restrict__ Kk, const int* __restrict__ pos) {
  const int idx = blockIdx.x * 256 + threadIdx.x;   // (bh, s, i) i fastest
  const int i = idx & 63;
  const int s = (idx >> 6) & (Ssz - 1);
  const int bh = idx >> 17;
  const int b = bh >> 4;
  const float p = (float)pos[b * Ssz + s];
  const float f = p * exp2f(-(float)i * 0.20762050593046014f); // log2(1e4)/64
  float sn, cs;
  sincosf(f, &sn, &cs);
  const size_t base = ((size_t)bh * Ssz + s) * Hd;
  float x1 = (float)Q[base + i], x2 = (float)Q[base + i + 64];
  Q[base + i]      = (bf16)(x1 * cs - x2 * sn);
  Q[base + i + 64] = (bf16)(x2 * cs + x1 * sn);
  x1 = (float)Kk[base + i]; x2 = (float)Kk[base + i + 64];
  Kk[base + i]      = (bf16)(x1 * cs - x2 * sn);
  Kk[base + i + 64] = (bf16)(x2 * cs + x1 * sn);
}

// ---------------- causal flash attention, 64 q-rows/block ------------------
__global__ __launch_bounds__(256, 2) void k_attn(const bf16* __restrict__ Q,
                                                 const bf16* __restrict__ Kg,
                                                 const bf16* __restrict__ Vg,
                                                 bf16* __restrict__ AO) {
  const int bh = blockIdx.y;
  const int qb = blockIdx.x * 64;
  const int tid = threadIdx.x, lane = tid & 63, wid = tid >> 6;
  const int frow = lane & 15, fk8 = (lane >> 4) * 8;
  __shared__ bf16 KsS[64][136];        // +8 pad: 2-way-max on score B-frag reads
  __shared__ bf16 VtS[128][72];        // transposed V, 8-wide XOR block swizzle
  __shared__ bf16 PsS[4][16][72];      // per-wave P for PV re-fragmenting
  const size_t hbase = (size_t)bh * Ssz * Hd;
  bf16x8 qf[4];
  {
    const bf16* qp = Q + hbase + (size_t)(qb + wid * 16 + frow) * Hd + fk8;
#pragma unroll
    for (int c = 0; c < 4; c++) qf[c] = *(const bf16x8*)(qp + c * 32);
  }
  float mr[4], lr[4];
#pragma unroll
  for (int r = 0; r < 4; r++) { mr[r] = -1e30f; lr[r] = 0.f; }
  f32x4 ao[8] = {};
  const int ntiles = blockIdx.x + 1;   // causal: kv tiles 0..qb/64
  const int vswz = (tid & 7) << 3;     // == ((hd>>3)&7)<<3 for this thread's hd block
  for (int t = 0; t < ntiles; ++t) {
    const int kv0 = t * 64;
    __syncthreads();                    // prior compute done before restage
#pragma unroll
    for (int p = 0; p < 4; p++) {       // K tile 64x128
      int flat = tid + p * 256;
      int row = flat >> 4, cg = (flat & 15) * 8;
      *(bf16x8*)&KsS[row][cg] = *(const bf16x8*)(Kg + hbase + (size_t)(kv0 + row) * Hd + cg);
    }
    {
      const int key0 = tid >> 4, cg = (tid & 15) * 8;
#pragma unroll
      for (int p = 0; p < 4; p++) {     // V tile transposed + swizzled
        const int key = key0 + p * 16;
        bf16x8 v = *(const bf16x8*)(Vg + hbase + (size_t)(kv0 + key) * Hd + cg);
#pragma unroll
        for (int j = 0; j < 8; j++) VtS[cg + j][key ^ vswz] = v[j];
      }
    }
    __syncthreads();
    // ---- scores: 16x64 per wave
    float sc[4][4];
#pragma unroll
    for (int nt = 0; nt < 4; nt++) {
      f32x4 a = {};
#pragma unroll
      for (int c = 0; c < 4; c++) {
        bf16x8 kf = *(const bf16x8*)&KsS[nt * 16 + frow][c * 32 + fk8];
        a = __builtin_amdgcn_mfma_f32_16x16x32_bf16(qf[c], kf, a, 0, 0, 0);
      }
      const int colg = kv0 + nt * 16 + frow;
#pragma unroll
      for (int r = 0; r < 4; r++) {
        const int rowg = qb + wid * 16 + (lane >> 4) * 4 + r;
        sc[nt][r] = (colg <= rowg) ? a[r] * kScale : -1e30f;
      }
    }
    // ---- online softmax (row stats across 16 lanes of each group)
    float pv[4][4];
#pragma unroll
    for (int r = 0; r < 4; r++) {
      float tm = fmaxf(fmaxf(sc[0][r], sc[1][r]), fmaxf(sc[2][r], sc[3][r]));
#pragma unroll
      for (int off = 1; off < 16; off <<= 1) tm = fmaxf(tm, __shfl_xor(tm, off));
      const float mn = fmaxf(mr[r], tm);
      const float scale = expf(mr[r] - mn);
      float ps = 0.f;
#pragma unroll
      for (int nt = 0; nt < 4; nt++) { pv[nt][r] = expf(sc[nt][r] - mn); ps += pv[nt][r]; }
#pragma unroll
      for (int off = 1; off < 16; off <<= 1) ps += __shfl_xor(ps, off);
      lr[r] = lr[r] * scale + ps;
      mr[r] = mn;
#pragma unroll
      for (int ht = 0; ht < 8; ht++) ao[ht][r] *= scale;
    }
    // ---- P -> LDS (re-fragment for PV A-operand)
#pragma unroll
    for (int nt = 0; nt < 4; nt++)
#pragma unroll
      for (int r = 0; r < 4; r++)
        PsS[wid][(lane >> 4) * 4 + r][nt * 16 + frow] = (bf16)pv[nt][r];
    asm volatile("s_waitcnt lgkmcnt(0)" ::: "memory");
    bf16x8 pf0 = *(const bf16x8*)&PsS[wid][frow][fk8];
    bf16x8 pf1 = *(const bf16x8*)&PsS[wid][frow][32 + fk8];
#pragma unroll
    for (int ht = 0; ht < 8; ht++) {
      const int swzr = ((2 * ht + (frow >> 3)) & 7) << 3;
      bf16x8 vf0 = *(const bf16x8*)&VtS[ht * 16 + frow][fk8 ^ swzr];
      ao[ht] = __builtin_amdgcn_mfma_f32_16x16x32_bf16(pf0, vf0, ao[ht], 0, 0, 0);
      bf16x8 vf1 = *(const bf16x8*)&VtS[ht * 16 + frow][(32 + fk8) ^ swzr];
      ao[ht] = __builtin_amdgcn_mfma_f32_16x16x32_bf16(pf1, vf1, ao[ht], 0, 0, 0);
    }
  }
  // ---- normalize + write [b*S+s][h*128+hd] bf16
  const int b = bh >> 4, h = bh & 15;
#pragma unroll
  for (int r = 0; r < 4; r++) {
    const int srow = qb + wid * 16 + (lane >> 4) * 4 + r;
    const float inv = 1.0f / lr[r];
    bf16* op = AO + ((size_t)b * Ssz + srow) * Hid + h * Hd + frow;
#pragma unroll
    for (int ht = 0; ht < 8; ht++) op[ht * 16] = (bf16)(ao[ht][r] * inv);
  }
}

extern "C" void kernel_launch(void* const* d_in, const int* in_sizes, int n_in,
                              void* d_out, int out_size, void* d_ws, size_t ws_size,
                              hipStream_t stream) {
  (void)in_sizes; (void)n_in; (void)out_size; (void)ws_size;
  const float* hidden   = (const float*)d_in[0];
  const int*   positions= (const int*)d_in[1];
  const float* wq = (const float*)d_in[2];
  const float* bq = (const float*)d_in[3];
  const float* wk = (const float*)d_in[4];
  const float* bk = (const float*)d_in[5];
  const float* wv = (const float*)d_in[6];
  const float* bv = (const float*)d_in[7];
  const float* wc = (const float*)d_in[8];
  float* out = (float*)d_out;

  char* ws = (char*)d_ws;
  bf16* WT  = (bf16*)ws;                                               // 4*Hid*Hid bf16
  bf16* Hbf = (bf16*)(ws + (size_t)4 * Hid * Hid * 2);                 // Mrows*Hid (reused as AO)
  bf16* Qb  = (bf16*)(ws + (size_t)4 * Hid * Hid * 2 + (size_t)Mrows * Hid * 2);
  bf16* Kb  = Qb + (size_t)Mrows * Hid;
  bf16* Vb  = Kb + (size_t)Mrows * Hid;

  k_cvt<<<dim3(Mrows * Hid / 4 / 256), dim3(256), 0, stream>>>(hidden, Hbf, Mrows * Hid / 4);
  k_wtrans<<<dim3(Hid / 32, Hid / 32, 4), dim3(32, 8), 0, stream>>>(wq, wk, wv, wc, WT);
  k_gemm<0><<<dim3(Hid / 128, Mrows / 128, 3), dim3(256), 0, stream>>>(
      Hbf, WT, bq, bk, bv, Qb, Kb, Vb, nullptr);
  k_rope<<<dim3(Bsz * NHd * Ssz * 64 / 256), dim3(256), 0, stream>>>(Qb, Kb, positions);
  k_attn<<<dim3(Ssz / 64, Bsz * NHd), dim3(256), 0, stream>>>(Qb, Kb, Vb, Hbf /*AO*/);
  k_gemm<1><<<dim3(Hid / 128, Mrows / 128, 1), dim3(256), 0, stream>>>(
      Hbf, WT + (size_t)3 * Hid * Hid, nullptr, nullptr, nullptr,
      nullptr, nullptr, nullptr, out);
}

// Round 2
// 317.264 us; speedup vs baseline: 1.3092x; 1.3092x over previous
//
#include <hip/hip_runtime.h>
#include <stdint.h>

constexpr int Bsz = 2;
constexpr int Ssz = 2048;
constexpr int Hid = 2048;
constexpr int NHd = 16;
constexpr int Hd  = 128;
constexpr int Mrows = Bsz * Ssz;                 // 4096
constexpr float kScale = 0.08838834764831845f;   // Hd^-0.5

typedef __bf16 bf16;
typedef __bf16 bf16x8 __attribute__((ext_vector_type(8)));
typedef __bf16 bf16x4 __attribute__((ext_vector_type(4)));
typedef float  f32x4  __attribute__((ext_vector_type(4)));
typedef float  f32x16 __attribute__((ext_vector_type(16)));

__device__ __forceinline__ void gload_lds16(const bf16* g, bf16* l) {
  __builtin_amdgcn_global_load_lds((const __attribute__((address_space(1))) void*)g,
                                   (__attribute__((address_space(3))) void*)l, 16, 0, 0);
}

__device__ __forceinline__ uint32_t pkbf(bf16 a, bf16 b) {
  union { bf16 hh[2]; uint32_t u; } x;
  x.hh[0] = a; x.hh[1] = b;
  return x.u;
}
__device__ __forceinline__ uint32_t pkff(float a, float b) {
  return pkbf((bf16)a, (bf16)b);
}

// ---------------- f32 -> bf16 bulk convert (4 elems/thread) ----------------
__global__ void k_cvt(const float* __restrict__ in, bf16* __restrict__ out, int n4) {
  int i = blockIdx.x * blockDim.x + threadIdx.x;
  if (i >= n4) return;
  float4 v = ((const float4*)in)[i];
  bf16x4 o = { (bf16)v.x, (bf16)v.y, (bf16)v.z, (bf16)v.w };
  ((bf16x4*)out)[i] = o;
}

// ------------- transpose 4 weights [K][N] f32 -> [N][K] bf16 ---------------
__global__ void k_wtrans(const float* __restrict__ w0, const float* __restrict__ w1,
                         const float* __restrict__ w2, const float* __restrict__ w3,
                         bf16* __restrict__ out) {
  __shared__ float tile[32][33];
  int z = blockIdx.z;
  const float* w = (z == 0) ? w0 : (z == 1) ? w1 : (z == 2) ? w2 : w3;
  bf16* o = out + (size_t)z * Hid * Hid;
  int n0 = blockIdx.x * 32, k0 = blockIdx.y * 32;
  int tx = threadIdx.x, ty = threadIdx.y;
#pragma unroll
  for (int i = 0; i < 4; i++)
    tile[ty + i * 8][tx] = w[(size_t)(k0 + ty + i * 8) * Hid + n0 + tx];
  __syncthreads();
#pragma unroll
  for (int i = 0; i < 4; i++)
    o[(size_t)(n0 + ty + i * 8) * Hid + k0 + tx] = (bf16)tile[tx][ty + i * 8];
}

// ---------------- m97-structure bf16 GEMM, 128x128 tile, BK=32 -------------
// MODE 0: C = A@W^T + bias -> scatter bf16 into [b][h][s][hd] (z picks q/k/v)
//         K (z==1) is additionally scaled by kScale*log2e (softmax in log2 domain)
// MODE 1: C = A@W^T -> f32 row-major d_out
template <int MODE>
__global__ __launch_bounds__(256, 2) void k_gemm(const bf16* __restrict__ A,
                                                 const bf16* __restrict__ Bt,
                                                 const float* __restrict__ biasq,
                                                 const float* __restrict__ biask,
                                                 const float* __restrict__ biasv,
                                                 bf16* __restrict__ Qo, bf16* __restrict__ Ko,
                                                 bf16* __restrict__ Vo, float* __restrict__ Fo) {
  constexpr int KK = Hid;
  const int z = blockIdx.z;
  const bf16* Bw = Bt + (size_t)z * Hid * Hid;
  const int m0 = blockIdx.y * 128, n0 = blockIdx.x * 128;
  __shared__ bf16 As[128][32];
  __shared__ bf16 Bs[128][32];
  const int tid = threadIdx.x;
  const int lane = tid & 63, wid = tid >> 6;
  const int wr = wid >> 1, wcc = wid & 1;
  const int srow = lane >> 2, scol = (lane & 3) * 8;
  const bf16* Ag = A + (size_t)(m0 + wid * 16 + srow) * KK + scol;
  const bf16* Bg = Bw + (size_t)(n0 + wid * 16 + srow) * KK + scol;
  const int frow = lane & 15, fk8 = (lane >> 4) * 8;
  f32x4 acc[4][4] = {};
  for (int k0 = 0; k0 < KK; k0 += 32) {
    __syncthreads();
    gload_lds16(Ag + k0, &As[wid * 16][0]);
    gload_lds16(Ag + (size_t)64 * KK + k0, &As[64 + wid * 16][0]);
    gload_lds16(Bg + k0, &Bs[wid * 16][0]);
    gload_lds16(Bg + (size_t)64 * KK + k0, &Bs[64 + wid * 16][0]);
    __syncthreads();
    bf16x8 af[4], bfr[4];
#pragma unroll
    for (int i = 0; i < 4; i++) af[i] = *(const bf16x8*)&As[wr * 64 + i * 16 + frow][fk8];
#pragma unroll
    for (int i = 0; i < 4; i++) bfr[i] = *(const bf16x8*)&Bs[wcc * 64 + i * 16 + frow][fk8];
#pragma unroll
    for (int mi = 0; mi < 4; mi++)
#pragma unroll
      for (int ni = 0; ni < 4; ni++)
        acc[mi][ni] = __builtin_amdgcn_mfma_f32_16x16x32_bf16(af[mi], bfr[ni], acc[mi][ni], 0, 0, 0);
  }
  if (MODE == 0) {
    const float* bias = (z == 0) ? biasq : (z == 1) ? biask : biasv;
    bf16* o = (z == 0) ? Qo : (z == 1) ? Ko : Vo;
    const float oscale = (z == 1) ? (float)(0.08838834764831845 * 1.4426950408889634) : 1.0f;
#pragma unroll
    for (int ni = 0; ni < 4; ni++) {
      const int col = n0 + wcc * 64 + ni * 16 + frow;
      const float bb_ = bias[col];
      const int h = col >> 7, hd = col & (Hd - 1);
#pragma unroll
      for (int mi = 0; mi < 4; mi++) {
#pragma unroll
        for (int r = 0; r < 4; r++) {
          const int row = m0 + wr * 64 + mi * 16 + (lane >> 4) * 4 + r;
          const int bb = row >> 11, ss = row & (Ssz - 1);
          o[(((size_t)bb * NHd + h) * Ssz + ss) * Hd + hd] = (bf16)((acc[mi][ni][r] + bb_) * oscale);
        }
      }
    }
  } else {
#pragma unroll
    for (int mi = 0; mi < 4; mi++)
#pragma unroll
      for (int ni = 0; ni < 4; ni++) {
        const int col = n0 + wcc * 64 + ni * 16 + frow;
#pragma unroll
        for (int r = 0; r < 4; r++) {
          const int row = m0 + wr * 64 + mi * 16 + (lane >> 4) * 4 + r;
          Fo[(size_t)row * Hid + col] = acc[mi][ni][r];
        }
      }
  }
}

// ---------------- RoPE (neox) on Q and K in place --------------------------
__global__ void k_rope(bf16* __restrict__ Q, bf16* __restrict__ Kk, const int* __restrict__ pos) {
  const int idx = blockIdx.x * 256 + threadIdx.x;   // (bh, s, i) i fastest
  const int i = idx & 63;
  const int s = (idx >> 6) & (Ssz - 1);
  const int bh = idx >> 17;
  const int b = bh >> 4;
  const float p = (float)pos[b * Ssz + s];
  const float f = p * exp2f(-(float)i * 0.20762050593046014f); // log2(1e4)/64
  float sn, cs;
  sincosf(f, &sn, &cs);
  const size_t base = ((size_t)bh * Ssz + s) * Hd;
  float x1 = (float)Q[base + i], x2 = (float)Q[base + i + 64];
  Q[base + i]      = (bf16)(x1 * cs - x2 * sn);
  Q[base + i + 64] = (bf16)(x2 * cs + x1 * sn);
  x1 = (float)Kk[base + i]; x2 = (float)Kk[base + i + 64];
  Kk[base + i]      = (bf16)(x1 * cs - x2 * sn);
  Kk[base + i + 64] = (bf16)(x2 * cs + x1 * sn);
}

// ------------- causal flash attention, swapped-QK, 32x32x16 MFMA -----------
// 4 waves x 32 q-rows = 128 q/block. K staged via global_load_lds with
// pre-swizzled source; V staged transposed (reg repack, b64 writes, pad+swz).
// Softmax per-lane (1 query/lane, halves duplicated), log2 domain
// (K pre-scaled by kScale*log2e in GEMM epilogue), defer-max THR=8.
__global__ __launch_bounds__(256, 2) void k_attn(const bf16* __restrict__ Qg,
                                                 const bf16* __restrict__ Kg,
                                                 const bf16* __restrict__ Vg,
                                                 bf16* __restrict__ AO) {
  const int bh = blockIdx.y;
  int qc = blockIdx.x;
  if (bh & 1) qc = 15 - qc;            // causal load balance across co-resident blocks
  const int tid = threadIdx.x, lane = tid & 63, w = tid >> 6;
  const int l31 = lane & 31, h = lane >> 5;
  __shared__ bf16 Ks[64 * 128];        // XOR-swizzled contents (16B granule by row&7)
  __shared__ bf16 Vt[128 * 72];        // V^T: [hd][key], pad 72, swz by (hd>>3)&7
  const size_t hbase = (size_t)bh * Ssz * Hd;
  const int q0 = qc * 128 + w * 32;    // wave's first query row
  // Q fragments: B-operand of swapped QK^T: lane holds Q[q0+l31][c*16+8h+0..7]
  bf16x8 qf[8];
  {
    const bf16* qp = Qg + hbase + (size_t)(q0 + l31) * Hd + h * 8;
#pragma unroll
    for (int c = 0; c < 8; c++) qf[c] = *(const bf16x8*)(qp + c * 16);
  }
  float m = -1e30f, lsum = 0.f;
  f32x16 o[4] = {};
  const int NT = 2 * (qc + 1);
  for (int t = 0; t < NT; ++t) {
    const int kv0 = t * 64;
    __syncthreads();                   // prior tile's LDS reads done
    // ---- stage K [64][128] via global_load_lds, source pre-swizzled
    {
      const bf16* Kt = Kg + hbase + (size_t)kv0 * Hd;
#pragma unroll
      for (int i = 0; i < 4; i++) {
        const int db  = (w * 4 + i) * 1024 + (lane << 4);
        const int row = db >> 8;
        const int cb  = (db & 255) ^ ((row & 7) << 4);
        gload_lds16(Kt + row * Hd + (cb >> 1), Ks + (w * 4 + i) * 512);
      }
    }
    // ---- stage V transposed: thread owns keys 4*(tid>>4)+0..3, hd (tid&15)*8..+7
    {
      const int r4  = (tid >> 4) << 2;
      const int hd0 = (tid & 15) << 3;
      bf16x8 vv[4];
#pragma unroll
      for (int p = 0; p < 4; p++)
        vv[p] = *(const bf16x8*)(Vg + hbase + (size_t)(kv0 + r4 + p) * Hd + hd0);
#pragma unroll
      for (int j = 0; j < 8; j++) {
        uint2 wv;
        wv.x = pkbf(vv[0][j], vv[1][j]);
        wv.y = pkbf(vv[2][j], vv[3][j]);
        const int hd = hd0 + j;
        const int cb = (r4 * 2) ^ (((hd >> 3) & 7) << 4);
        *(uint2*)((char*)Vt + hd * 144 + cb) = wv;
      }
    }
    __syncthreads();                   // staging visible
    if (kv0 <= q0 + 31) {              // wave-uniform: skip fully-masked tiles
      // ---- QK^T swapped: S[key][q] = K·Q^T, accumulate over 8 hd-chunks
      f32x16 s0 = {}, s1 = {};
#pragma unroll
      for (int c = 0; c < 8; c++) {
        const int cb = (c * 32 + h * 16) ^ ((l31 & 7) << 4);
        bf16x8 k0 = *(const bf16x8*)((const char*)Ks + l31 * 256 + cb);
        bf16x8 k1 = *(const bf16x8*)((const char*)Ks + (32 + l31) * 256 + cb);
        s0 = __builtin_amdgcn_mfma_f32_32x32x16_bf16(k0, qf[c], s0, 0, 0, 0);
        s1 = __builtin_amdgcn_mfma_f32_32x32x16_bf16(k1, qf[c], s1, 0, 0, 0);
      }
      // ---- causal mask (only diagonal-band tiles)
      if (kv0 + 63 > q0) {
        const int qg = q0 + l31;
        const int kb = kv0 + 4 * h;
#pragma unroll
        for (int r = 0; r < 16; r++) {
          const int cr = (r & 3) + 8 * (r >> 2);
          if (kb + cr > qg)      s0[r] = -1e30f;
          if (kb + 32 + cr > qg) s1[r] = -1e30f;
        }
      }
      // ---- online softmax, log2 domain, per-lane row state
      float tm = s0[0];
#pragma unroll
      for (int r = 1; r < 16; r++) tm = fmaxf(tm, s0[r]);
#pragma unroll
      for (int r = 0; r < 16; r++) tm = fmaxf(tm, s1[r]);
      tm = fmaxf(tm, __shfl_xor(tm, 32));
      if (!__all(tm - m <= 8.0f)) {    // defer-max (T13)
        const float mn = fmaxf(m, tm);
        const float rs = exp2f(m - mn);
        m = mn; lsum *= rs;
#pragma unroll
        for (int ct = 0; ct < 4; ct++)
#pragma unroll
          for (int r = 0; r < 16; r++) o[ct][r] *= rs;
      }
      float ps = 0.f;
#pragma unroll
      for (int r = 0; r < 16; r++) { s0[r] = exp2f(s0[r] - m); ps += s0[r]; }
#pragma unroll
      for (int r = 0; r < 16; r++) { s1[r] = exp2f(s1[r] - m); ps += s1[r]; }
      ps += __shfl_xor(ps, 32);
      lsum += ps;
      // ---- P -> bf16 A-frags: pack pairs + one cross-half exchange per word
      uint32_t gw[8][2];
#pragma unroll
      for (int g = 0; g < 4; g++) {
        gw[g][0]     = pkff(s0[4 * g], s0[4 * g + 1]);
        gw[g][1]     = pkff(s0[4 * g + 2], s0[4 * g + 3]);
        gw[4 + g][0] = pkff(s1[4 * g], s1[4 * g + 1]);
        gw[4 + g][1] = pkff(s1[4 * g + 2], s1[4 * g + 3]);
      }
#pragma unroll
      for (int kc = 0; kc < 4; kc++) {
        const uint32_t a0 = gw[2 * kc][0], a1 = gw[2 * kc][1];
        const uint32_t b0 = gw[2 * kc + 1][0], b1 = gw[2 * kc + 1][1];
        const uint32_t sd0 = h ? a0 : b0, sd1 = h ? a1 : b1;
        const uint32_t r0 = (uint32_t)__shfl_xor((int)sd0, 32);
        const uint32_t r1 = (uint32_t)__shfl_xor((int)sd1, 32);
        union { uint32_t u[4]; bf16x8 v; } pa;
        pa.u[0] = h ? r0 : a0; pa.u[1] = h ? r1 : a1;
        pa.u[2] = h ? b0 : r0; pa.u[3] = h ? b1 : r1;
#pragma unroll
        for (int ct = 0; ct < 4; ct++) {
          const int row = ct * 32 + l31;
          const int cb = (kc * 32 + h * 16) ^ (((row >> 3) & 7) << 4);
          bf16x8 vf = *(const bf16x8*)((const char*)Vt + row * 144 + cb);
          o[ct] = __builtin_amdgcn_mfma_f32_32x32x16_bf16(pa.v, vf, o[ct], 0, 0, 0);
        }
      }
    }
  }
  // ---- epilogue: redistribute 1/l to O's row layout, store bf16
  const float linv = 1.0f / lsum;
  float li[16];
#pragma unroll
  for (int r = 0; r < 16; r++)
    li[r] = __shfl(linv, (r & 3) + 8 * (r >> 2) + 4 * h);
  const int b = bh >> 4, hh = bh & 15;
#pragma unroll
  for (int ct = 0; ct < 4; ct++) {
#pragma unroll
    for (int r = 0; r < 16; r++) {
      const int qrow = q0 + (r & 3) + 8 * (r >> 2) + 4 * h;
      AO[((size_t)b * Ssz + qrow) * Hid + hh * Hd + ct * 32 + l31] = (bf16)(o[ct][r] * li[r]);
    }
  }
}

extern "C" void kernel_launch(void* const* d_in, const int* in_sizes, int n_in,
                              void* d_out, int out_size, void* d_ws, size_t ws_size,
                              hipStream_t stream) {
  (void)in_sizes; (void)n_in; (void)out_size; (void)ws_size;
  const float* hidden   = (const float*)d_in[0];
  const int*   positions= (const int*)d_in[1];
  const float* wq = (const float*)d_in[2];
  const float* bq = (const float*)d_in[3];
  const float* wk = (const float*)d_in[4];
  const float* bk = (const float*)d_in[5];
  const float* wv = (const float*)d_in[6];
  const float* bv = (const float*)d_in[7];
  const float* wc = (const float*)d_in[8];
  float* out = (float*)d_out;

  char* ws = (char*)d_ws;
  bf16* WT  = (bf16*)ws;                                               // 4*Hid*Hid bf16
  bf16* Hbf = (bf16*)(ws + (size_t)4 * Hid * Hid * 2);                 // Mrows*Hid (reused as AO)
  bf16* Qb  = (bf16*)(ws + (size_t)4 * Hid * Hid * 2 + (size_t)Mrows * Hid * 2);
  bf16* Kb  = Qb + (size_t)Mrows * Hid;
  bf16* Vb  = Kb + (size_t)Mrows * Hid;

  k_cvt<<<dim3(Mrows * Hid / 4 / 256), dim3(256), 0, stream>>>(hidden, Hbf, Mrows * Hid / 4);
  k_wtrans<<<dim3(Hid / 32, Hid / 32, 4), dim3(32, 8), 0, stream>>>(wq, wk, wv, wc, WT);
  k_gemm<0><<<dim3(Hid / 128, Mrows / 128, 3), dim3(256), 0, stream>>>(
      Hbf, WT, bq, bk, bv, Qb, Kb, Vb, nullptr);
  k_rope<<<dim3(Bsz * NHd * Ssz * 64 / 256), dim3(256), 0, stream>>>(Qb, Kb, positions);
  k_attn<<<dim3(16, Bsz * NHd), dim3(256), 0, stream>>>(Qb, Kb, Vb, Hbf /*AO*/);
  k_gemm<1><<<dim3(Hid / 128, Mrows / 128, 1), dim3(256), 0, stream>>>(
      Hbf, WT + (size_t)3 * Hid * Hid, nullptr, nullptr, nullptr,
      nullptr, nullptr, nullptr, out);
}

// Round 3
// 301.173 us; speedup vs baseline: 1.3792x; 1.0534x over previous
//
#include <hip/hip_runtime.h>
#include <stdint.h>

constexpr int Bsz = 2;
constexpr int Ssz = 2048;
constexpr int Hid = 2048;
constexpr int NHd = 16;
constexpr int Hd  = 128;
constexpr int Mrows = Bsz * Ssz;                 // 4096
constexpr float kScale = 0.08838834764831845f;   // Hd^-0.5

typedef __bf16 bf16;
typedef __bf16 bf16x8 __attribute__((ext_vector_type(8)));
typedef __bf16 bf16x4 __attribute__((ext_vector_type(4)));
typedef float  f32x4  __attribute__((ext_vector_type(4)));
typedef float  f32x16 __attribute__((ext_vector_type(16)));

__device__ __forceinline__ void gload_lds16(const bf16* g, bf16* l) {
  __builtin_amdgcn_global_load_lds((const __attribute__((address_space(1))) void*)g,
                                   (__attribute__((address_space(3))) void*)l, 16, 0, 0);
}

__device__ __forceinline__ uint32_t pkbf(bf16 a, bf16 b) {
  union { bf16 hh[2]; uint32_t u; } x;
  x.hh[0] = a; x.hh[1] = b;
  return x.u;
}
__device__ __forceinline__ uint32_t pkff(float a, float b) {
  return pkbf((bf16)a, (bf16)b);
}

// ---------------- f32 -> bf16 bulk convert (4 elems/thread) ----------------
__global__ void k_cvt(const float* __restrict__ in, bf16* __restrict__ out, int n4) {
  int i = blockIdx.x * blockDim.x + threadIdx.x;
  if (i >= n4) return;
  float4 v = ((const float4*)in)[i];
  bf16x4 o = { (bf16)v.x, (bf16)v.y, (bf16)v.z, (bf16)v.w };
  ((bf16x4*)out)[i] = o;
}

// ------------- transpose 4 weights [K][N] f32 -> [N][K] bf16 ---------------
__global__ void k_wtrans(const float* __restrict__ w0, const float* __restrict__ w1,
                         const float* __restrict__ w2, const float* __restrict__ w3,
                         bf16* __restrict__ out) {
  __shared__ float tile[32][33];
  int z = blockIdx.z;
  const float* w = (z == 0) ? w0 : (z == 1) ? w1 : (z == 2) ? w2 : w3;
  bf16* o = out + (size_t)z * Hid * Hid;
  int n0 = blockIdx.x * 32, k0 = blockIdx.y * 32;
  int tx = threadIdx.x, ty = threadIdx.y;
#pragma unroll
  for (int i = 0; i < 4; i++)
    tile[ty + i * 8][tx] = w[(size_t)(k0 + ty + i * 8) * Hid + n0 + tx];
  __syncthreads();
#pragma unroll
  for (int i = 0; i < 4; i++)
    o[(size_t)(n0 + ty + i * 8) * Hid + k0 + tx] = (bf16)tile[tx][ty + i * 8];
}

// ---- swizzled-LDS fragment read: element (row,k) lives at byte
//      row*128 + (((k>>3) ^ (row&7))<<4) + (k&7)*2
__device__ __forceinline__ bf16x8 rdfrag(const bf16* t, int row, int kslot) {
  return *(const bf16x8*)((const char*)t + row * 128 + (((kslot ^ (row & 7)) & 7) << 4));
}

// ---- stage NB 1KB-blocks of a [rows][64] bf16 K-slice into linear LDS,
//      source pre-inverse-swizzled so reads use rdfrag (rule #21)
template <int NB>
__device__ __forceinline__ void stageN(const bf16* g, bf16* l, int w, int lane) {
  const int rsub = lane >> 3;
  const int slot = (lane & 7) ^ rsub;
#pragma unroll
  for (int j = 0; j < NB; ++j) {
    const int blk = w * NB + j;
    gload_lds16(g + (size_t)(blk * 8 + rsub) * Hid + slot * 8, l + blk * 512);
  }
}

#define PH_SYNC()                                      \
  __builtin_amdgcn_s_barrier();                        \
  asm volatile("s_waitcnt lgkmcnt(0)" ::: "memory");   \
  __builtin_amdgcn_sched_barrier(0);

// ------------- phased-pipeline bf16 GEMM: 256x128 tile, BK=64, 8 waves -----
// MODE 0: fused QKV (N=6144): C = A@W^T + bias -> bf16 scatter [b][h][s][hd],
//         K output scaled by kScale*log2e (softmax in log2 domain)
// MODE 1: C = A@W^T -> f32 row-major (output projection)
template <int MODE>
__global__ __launch_bounds__(512, 2) void k_gemm(const bf16* __restrict__ A,
                                                 const bf16* __restrict__ Bt,
                                                 const float* __restrict__ biasq,
                                                 const float* __restrict__ biask,
                                                 const float* __restrict__ biasv,
                                                 bf16* __restrict__ Qo, bf16* __restrict__ Ko,
                                                 bf16* __restrict__ Vo, float* __restrict__ Fo) {
  constexpr int KK = Hid;
  constexpr int NT = KK / 64;
  __shared__ bf16 smA[2][256 * 64];
  __shared__ bf16 smB[2][128 * 64];
  // XCD-aware swizzle (T1; both grids are multiples of 8)
  const int nwg = gridDim.x * gridDim.y;
  int flat = blockIdx.y * gridDim.x + blockIdx.x;
  flat = (flat & 7) * (nwg >> 3) + (flat >> 3);
  const int m0 = (flat / gridDim.x) * 256;
  const int n0 = (flat % gridDim.x) * 128;
  const int tid = threadIdx.x, lane = tid & 63, w = tid >> 6;
  const int wm = w >> 1, wn = w & 1;
  const int frow = lane & 15, a4 = lane >> 4;
  const bf16* Ag = A + (size_t)m0 * KK;
  const bf16* Bg = Bt + (size_t)n0 * KK;
  f32x4 acc[4][4] = {};
  // prologue: tile 0 -> buf0
  stageN<4>(Ag, smA[0], w, lane);
  stageN<2>(Bg, smB[0], w, lane);
  __syncthreads();
#pragma unroll 2
  for (int kt = 0; kt < NT; ++kt) {
    const int cur = kt & 1;
    const bf16* At = smA[cur];
    const bf16* Btl = smB[cur];
    bf16* As2 = smA[cur ^ 1];
    bf16* Bs2 = smB[cur ^ 1];
    const int kn = (kt + 1 < NT ? kt + 1 : kt) * 64;
    bf16x8 af[2][2], bfr[4][2];
    // ---- phase 0: A rows 0-1, all B; stage next A
#pragma unroll
    for (int mi = 0; mi < 2; ++mi)
#pragma unroll
      for (int kk = 0; kk < 2; ++kk)
        af[mi][kk] = rdfrag(At, wm * 64 + mi * 16 + frow, kk * 4 + a4);
#pragma unroll
    for (int ni = 0; ni < 4; ++ni)
#pragma unroll
      for (int kk = 0; kk < 2; ++kk)
        bfr[ni][kk] = rdfrag(Btl, wn * 64 + ni * 16 + frow, kk * 4 + a4);
    stageN<4>(Ag + kn, As2, w, lane);
    PH_SYNC();
    __builtin_amdgcn_s_setprio(1);
#pragma unroll
    for (int mi = 0; mi < 2; ++mi)
#pragma unroll
      for (int ni = 0; ni < 4; ++ni)
#pragma unroll
        for (int kk = 0; kk < 2; ++kk)
          acc[mi][ni] = __builtin_amdgcn_mfma_f32_16x16x32_bf16(
              af[mi][kk], bfr[ni][kk], acc[mi][ni], 0, 0, 0);
    __builtin_amdgcn_s_setprio(0);
    __builtin_amdgcn_s_barrier();
    // ---- phase 1: A rows 2-3; stage next B
#pragma unroll
    for (int mi = 0; mi < 2; ++mi)
#pragma unroll
      for (int kk = 0; kk < 2; ++kk)
        af[mi][kk] = rdfrag(At, wm * 64 + (2 + mi) * 16 + frow, kk * 4 + a4);
    stageN<2>(Bg + kn, Bs2, w, lane);
    PH_SYNC();
    __builtin_amdgcn_s_setprio(1);
#pragma unroll
    for (int mi = 0; mi < 2; ++mi)
#pragma unroll
      for (int ni = 0; ni < 4; ++ni)
#pragma unroll
        for (int kk = 0; kk < 2; ++kk)
          acc[2 + mi][ni] = __builtin_amdgcn_mfma_f32_16x16x32_bf16(
              af[mi][kk], bfr[ni][kk], acc[2 + mi][ni], 0, 0, 0);
    __builtin_amdgcn_s_setprio(0);
    asm volatile("s_waitcnt vmcnt(0)" ::: "memory");
    __builtin_amdgcn_s_barrier();
  }
  // ---- epilogue
  if (MODE == 0) {
    const int z = n0 >> 11;                      // 128-wide tile: one weight matrix
    const float* bias = (z == 0) ? biasq : (z == 1) ? biask : biasv;
    bf16* o = (z == 0) ? Qo : (z == 1) ? Ko : Vo;
    const float oscale = (z == 1) ? (float)(0.08838834764831845 * 1.4426950408889634) : 1.0f;
#pragma unroll
    for (int ni = 0; ni < 4; ++ni) {
      const int col = n0 + wn * 64 + ni * 16 + frow;
      const float bb_ = bias[col & 2047];
      const int h = (col >> 7) & 15, hd = col & (Hd - 1);
#pragma unroll
      for (int mi = 0; mi < 4; ++mi) {
#pragma unroll
        for (int r = 0; r < 4; ++r) {
          const int row = m0 + wm * 64 + mi * 16 + a4 * 4 + r;
          const int bb = row >> 11, ss = row & (Ssz - 1);
          o[(((size_t)bb * NHd + h) * Ssz + ss) * Hd + hd] = (bf16)((acc[mi][ni][r] + bb_) * oscale);
        }
      }
    }
  } else {
#pragma unroll
    for (int mi = 0; mi < 4; ++mi)
#pragma unroll
      for (int ni = 0; ni < 4; ++ni) {
        const int col = n0 + wn * 64 + ni * 16 + frow;
#pragma unroll
        for (int r = 0; r < 4; ++r) {
          const int row = m0 + wm * 64 + mi * 16 + a4 * 4 + r;
          Fo[(size_t)row * Hid + col] = acc[mi][ni][r];
        }
      }
  }
}

// ---------------- RoPE (neox) on Q and K in place --------------------------
__global__ void k_rope(bf16* __restrict__ Q, bf16* __restrict__ Kk, const int* __restrict__ pos) {
  const int idx = blockIdx.x * 256 + threadIdx.x;   // (bh, s, i) i fastest
  const int i = idx & 63;
  const int s = (idx >> 6) & (Ssz - 1);
  const int bh = idx >> 17;
  const int b = bh >> 4;
  const float p = (float)pos[b * Ssz + s];
  const float f = p * exp2f(-(float)i * 0.20762050593046014f); // log2(1e4)/64
  float sn, cs;
  sincosf(f, &sn, &cs);
  const size_t base = ((size_t)bh * Ssz + s) * Hd;
  float x1 = (float)Q[base + i], x2 = (float)Q[base + i + 64];
  Q[base + i]      = (bf16)(x1 * cs - x2 * sn);
  Q[base + i + 64] = (bf16)(x2 * cs + x1 * sn);
  x1 = (float)Kk[base + i]; x2 = (float)Kk[base + i + 64];
  Kk[base + i]      = (bf16)(x1 * cs - x2 * sn);
  Kk[base + i + 64] = (bf16)(x2 * cs + x1 * sn);
}

// ------------- causal flash attention, swapped-QK, 32x32x16 MFMA -----------
__global__ __launch_bounds__(256, 2) void k_attn(const bf16* __restrict__ Qg,
                                                 const bf16* __restrict__ Kg,
                                                 const bf16* __restrict__ Vg,
                                                 bf16* __restrict__ AO) {
  const int bh = blockIdx.y;
  int qc = blockIdx.x;
  if (bh & 1) qc = 15 - qc;            // causal load balance across co-resident blocks
  const int tid = threadIdx.x, lane = tid & 63, w = tid >> 6;
  const int l31 = lane & 31, h = lane >> 5;
  __shared__ bf16 Ks[64 * 128];        // XOR-swizzled contents (16B granule by row&7)
  __shared__ bf16 Vt[128 * 72];        // V^T: [hd][key], pad 72, swz by (hd>>3)&7
  const size_t hbase = (size_t)bh * Ssz * Hd;
  const int q0 = qc * 128 + w * 32;    // wave's first query row
  bf16x8 qf[8];
  {
    const bf16* qp = Qg + hbase + (size_t)(q0 + l31) * Hd + h * 8;
#pragma unroll
    for (int c = 0; c < 8; c++) qf[c] = *(const bf16x8*)(qp + c * 16);
  }
  float m = -1e30f, lsum = 0.f;
  f32x16 o[4] = {};
  const int NT = 2 * (qc + 1);
  for (int t = 0; t < NT; ++t) {
    const int kv0 = t * 64;
    __syncthreads();                   // prior tile's LDS reads done
    {
      const bf16* Kt = Kg + hbase + (size_t)kv0 * Hd;
#pragma unroll
      for (int i = 0; i < 4; i++) {
        const int db  = (w * 4 + i) * 1024 + (lane << 4);
        const int row = db >> 8;
        const int cb  = (db & 255) ^ ((row & 7) << 4);
        gload_lds16(Kt + row * Hd + (cb >> 1), Ks + (w * 4 + i) * 512);
      }
    }
    {
      const int r4  = (tid >> 4) << 2;
      const int hd0 = (tid & 15) << 3;
      bf16x8 vv[4];
#pragma unroll
      for (int p = 0; p < 4; p++)
        vv[p] = *(const bf16x8*)(Vg + hbase + (size_t)(kv0 + r4 + p) * Hd + hd0);
#pragma unroll
      for (int j = 0; j < 8; j++) {
        uint2 wv;
        wv.x = pkbf(vv[0][j], vv[1][j]);
        wv.y = pkbf(vv[2][j], vv[3][j]);
        const int hd = hd0 + j;
        const int cb = (r4 * 2) ^ (((hd >> 3) & 7) << 4);
        *(uint2*)((char*)Vt + hd * 144 + cb) = wv;
      }
    }
    __syncthreads();                   // staging visible
    if (kv0 <= q0 + 31) {              // wave-uniform: skip fully-masked tiles
      f32x16 s0 = {}, s1 = {};
#pragma unroll
      for (int c = 0; c < 8; c++) {
        const int cb = (c * 32 + h * 16) ^ ((l31 & 7) << 4);
        bf16x8 k0 = *(const bf16x8*)((const char*)Ks + l31 * 256 + cb);
        bf16x8 k1 = *(const bf16x8*)((const char*)Ks + (32 + l31) * 256 + cb);
        s0 = __builtin_amdgcn_mfma_f32_32x32x16_bf16(k0, qf[c], s0, 0, 0, 0);
        s1 = __builtin_amdgcn_mfma_f32_32x32x16_bf16(k1, qf[c], s1, 0, 0, 0);
      }
      if (kv0 + 63 > q0) {
        const int qg = q0 + l31;
        const int kb = kv0 + 4 * h;
#pragma unroll
        for (int r = 0; r < 16; r++) {
          const int cr = (r & 3) + 8 * (r >> 2);
          if (kb + cr > qg)      s0[r] = -1e30f;
          if (kb + 32 + cr > qg) s1[r] = -1e30f;
        }
      }
      float tm = s0[0];
#pragma unroll
      for (int r = 1; r < 16; r++) tm = fmaxf(tm, s0[r]);
#pragma unroll
      for (int r = 0; r < 16; r++) tm = fmaxf(tm, s1[r]);
      tm = fmaxf(tm, __shfl_xor(tm, 32));
      if (!__all(tm - m <= 8.0f)) {    // defer-max (T13)
        const float mn = fmaxf(m, tm);
        const float rs = exp2f(m - mn);
        m = mn; lsum *= rs;
#pragma unroll
        for (int ct = 0; ct < 4; ct++)
#pragma unroll
          for (int r = 0; r < 16; r++) o[ct][r] *= rs;
      }
      float ps = 0.f;
#pragma unroll
      for (int r = 0; r < 16; r++) { s0[r] = exp2f(s0[r] - m); ps += s0[r]; }
#pragma unroll
      for (int r = 0; r < 16; r++) { s1[r] = exp2f(s1[r] - m); ps += s1[r]; }
      ps += __shfl_xor(ps, 32);
      lsum += ps;
      uint32_t gw[8][2];
#pragma unroll
      for (int g = 0; g < 4; g++) {
        gw[g][0]     = pkff(s0[4 * g], s0[4 * g + 1]);
        gw[g][1]     = pkff(s0[4 * g + 2], s0[4 * g + 3]);
        gw[4 + g][0] = pkff(s1[4 * g], s1[4 * g + 1]);
        gw[4 + g][1] = pkff(s1[4 * g + 2], s1[4 * g + 3]);
      }
#pragma unroll
      for (int kc = 0; kc < 4; kc++) {
        const uint32_t a0 = gw[2 * kc][0], a1 = gw[2 * kc][1];
        const uint32_t b0 = gw[2 * kc + 1][0], b1 = gw[2 * kc + 1][1];
        const uint32_t sd0 = h ? a0 : b0, sd1 = h ? a1 : b1;
        const uint32_t r0 = (uint32_t)__shfl_xor((int)sd0, 32);
        const uint32_t r1 = (uint32_t)__shfl_xor((int)sd1, 32);
        union { uint32_t u[4]; bf16x8 v; } pa;
        pa.u[0] = h ? r0 : a0; pa.u[1] = h ? r1 : a1;
        pa.u[2] = h ? b0 : r0; pa.u[3] = h ? b1 : r1;
#pragma unroll
        for (int ct = 0; ct < 4; ct++) {
          const int row = ct * 32 + l31;
          const int cb = (kc * 32 + h * 16) ^ (((row >> 3) & 7) << 4);
          bf16x8 vf = *(const bf16x8*)((const char*)Vt + row * 144 + cb);
          o[ct] = __builtin_amdgcn_mfma_f32_32x32x16_bf16(pa.v, vf, o[ct], 0, 0, 0);
        }
      }
    }
  }
  const float linv = 1.0f / lsum;
  float li[16];
#pragma unroll
  for (int r = 0; r < 16; r++)
    li[r] = __shfl(linv, (r & 3) + 8 * (r >> 2) + 4 * h);
  const int b = bh >> 4, hh = bh & 15;
#pragma unroll
  for (int ct = 0; ct < 4; ct++) {
#pragma unroll
    for (int r = 0; r < 16; r++) {
      const int qrow = q0 + (r & 3) + 8 * (r >> 2) + 4 * h;
      AO[((size_t)b * Ssz + qrow) * Hid + hh * Hd + ct * 32 + l31] = (bf16)(o[ct][r] * li[r]);
    }
  }
}

extern "C" void kernel_launch(void* const* d_in, const int* in_sizes, int n_in,
                              void* d_out, int out_size, void* d_ws, size_t ws_size,
                              hipStream_t stream) {
  (void)in_sizes; (void)n_in; (void)out_size; (void)ws_size;
  const float* hidden   = (const float*)d_in[0];
  const int*   positions= (const int*)d_in[1];
  const float* wq = (const float*)d_in[2];
  const float* bq = (const float*)d_in[3];
  const float* wk = (const float*)d_in[4];
  const float* bk = (const float*)d_in[5];
  const float* wv = (const float*)d_in[6];
  const float* bv = (const float*)d_in[7];
  const float* wc = (const float*)d_in[8];
  float* out = (float*)d_out;

  char* ws = (char*)d_ws;
  bf16* WT  = (bf16*)ws;                                               // 4*Hid*Hid bf16 (q,k,v,c)
  bf16* Hbf = (bf16*)(ws + (size_t)4 * Hid * Hid * 2);                 // Mrows*Hid (reused as AO)
  bf16* Qb  = (bf16*)(ws + (size_t)4 * Hid * Hid * 2 + (size_t)Mrows * Hid * 2);
  bf16* Kb  = Qb + (size_t)Mrows * Hid;
  bf16* Vb  = Kb + (size_t)Mrows * Hid;

  k_cvt<<<dim3(Mrows * Hid / 4 / 256), dim3(256), 0, stream>>>(hidden, Hbf, Mrows * Hid / 4);
  k_wtrans<<<dim3(Hid / 32, Hid / 32, 4), dim3(32, 8), 0, stream>>>(wq, wk, wv, wc, WT);
  // fused QKV: N = 6144, grid 48x16 = 768 blocks (3 full CU-rounds)
  k_gemm<0><<<dim3(48, 16), dim3(512), 0, stream>>>(
      Hbf, WT, bq, bk, bv, Qb, Kb, Vb, nullptr);
  k_rope<<<dim3(Bsz * NHd * Ssz * 64 / 256), dim3(256), 0, stream>>>(Qb, Kb, positions);
  k_attn<<<dim3(16, Bsz * NHd), dim3(256), 0, stream>>>(Qb, Kb, Vb, Hbf /*AO*/);
  // output projection: grid 16x16 = 256 blocks (1 full CU-round)
  k_gemm<1><<<dim3(16, 16), dim3(512), 0, stream>>>(
      Hbf, WT + (size_t)3 * Hid * Hid, nullptr, nullptr, nullptr,
      nullptr, nullptr, nullptr, out);
}

// Round 4
// 293.463 us; speedup vs baseline: 1.4154x; 1.0263x over previous
//
#include <hip/hip_runtime.h>
#include <stdint.h>

constexpr int Bsz = 2;
constexpr int Ssz = 2048;
constexpr int Hid = 2048;
constexpr int NHd = 16;
constexpr int Hd  = 128;
constexpr int Mrows = Bsz * Ssz;                 // 4096

typedef __bf16 bf16;
typedef __bf16 bf16x8 __attribute__((ext_vector_type(8)));
typedef __bf16 bf16x4 __attribute__((ext_vector_type(4)));
typedef float  f32x4  __attribute__((ext_vector_type(4)));
typedef float  f32x16 __attribute__((ext_vector_type(16)));

__device__ __forceinline__ void gload_lds16(const bf16* g, bf16* l) {
  __builtin_amdgcn_global_load_lds((const __attribute__((address_space(1))) void*)g,
                                   (__attribute__((address_space(3))) void*)l, 16, 0, 0);
}

__device__ __forceinline__ uint32_t pkbf(bf16 a, bf16 b) {
  union { bf16 hh[2]; uint32_t u; } x;
  x.hh[0] = a; x.hh[1] = b;
  return x.u;
}
__device__ __forceinline__ uint32_t pkff(float a, float b) {
  return pkbf((bf16)a, (bf16)b);
}

// ---------------- f32 -> bf16 bulk convert (4 elems/thread) ----------------
__global__ void k_cvt(const float* __restrict__ in, bf16* __restrict__ out, int n4) {
  int i = blockIdx.x * blockDim.x + threadIdx.x;
  if (i >= n4) return;
  float4 v = ((const float4*)in)[i];
  bf16x4 o = { (bf16)v.x, (bf16)v.y, (bf16)v.z, (bf16)v.w };
  ((bf16x4*)out)[i] = o;
}

// ------------- transpose 4 weights [K][N] f32 -> [N][K] bf16 ---------------
__global__ void k_wtrans(const float* __restrict__ w0, const float* __restrict__ w1,
                         const float* __restrict__ w2, const float* __restrict__ w3,
                         bf16* __restrict__ out) {
  __shared__ float tile[32][33];
  int z = blockIdx.z;
  const float* w = (z == 0) ? w0 : (z == 1) ? w1 : (z == 2) ? w2 : w3;
  bf16* o = out + (size_t)z * Hid * Hid;
  int n0 = blockIdx.x * 32, k0 = blockIdx.y * 32;
  int tx = threadIdx.x, ty = threadIdx.y;
#pragma unroll
  for (int i = 0; i < 4; i++)
    tile[ty + i * 8][tx] = w[(size_t)(k0 + ty + i * 8) * Hid + n0 + tx];
  __syncthreads();
#pragma unroll
  for (int i = 0; i < 4; i++)
    o[(size_t)(n0 + ty + i * 8) * Hid + k0 + tx] = (bf16)tile[tx][ty + i * 8];
}

// ---- swizzled-LDS fragment read: element (row,k) lives at byte
//      row*128 + (((k>>3) ^ (row&7))<<4) + (k&7)*2
__device__ __forceinline__ bf16x8 rdfrag(const bf16* t, int row, int kslot) {
  return *(const bf16x8*)((const char*)t + row * 128 + (((kslot ^ (row & 7)) & 7) << 4));
}

// ---- stage NB 1KB-blocks of a [rows][64] bf16 K-slice into linear LDS,
//      source pre-inverse-swizzled so reads use rdfrag (rule #21)
template <int NB>
__device__ __forceinline__ void stageN(const bf16* g, bf16* l, int w, int lane) {
  const int rsub = lane >> 3;
  const int slot = (lane & 7) ^ rsub;
#pragma unroll
  for (int j = 0; j < NB; ++j) {
    const int blk = w * NB + j;
    gload_lds16(g + (size_t)(blk * 8 + rsub) * Hid + slot * 8, l + blk * 512);
  }
}

#define PH_SYNC()                                      \
  __builtin_amdgcn_s_barrier();                        \
  asm volatile("s_waitcnt lgkmcnt(0)" ::: "memory");   \
  __builtin_amdgcn_sched_barrier(0);

// ------- counted-vmcnt pipelined bf16 GEMM: 256x128 tile, BK=64, 8 waves ---
// Triple-buffered LDS; tile t+2 staged during tile t; only wait is vmcnt(6)
// at the K-step boundary (completes t+1, leaves t+2 in flight). Never drains.
// MODE 0: fused QKV (N=6144): C = A@W^T + bias -> bf16 scatter [b][h][s][hd],
//         K output scaled by kScale*log2e (softmax in log2 domain)
// MODE 1: C = A@W^T -> f32 row-major (output projection)
// CHM/CHN: per-XCD chunk dims (in 256-row / 128-col tiles) for T1 2D blocking.
template <int MODE, int CHM, int CHN>
__global__ __launch_bounds__(512, 1) void k_gemm(const bf16* __restrict__ A,
                                                 const bf16* __restrict__ Bt,
                                                 const float* __restrict__ biasq,
                                                 const float* __restrict__ biask,
                                                 const float* __restrict__ biasv,
                                                 bf16* __restrict__ Qo, bf16* __restrict__ Ko,
                                                 bf16* __restrict__ Vo, float* __restrict__ Fo) {
  constexpr int KK = Hid;
  constexpr int NT = KK / 64;
  __shared__ bf16 smA[3][256 * 64];   // 96 KB
  __shared__ bf16 smB[3][128 * 64];   // 48 KB
  // T1: 2D chunk per XCD (hw dispatch id % 8 -> XCD)
  const int hw = blockIdx.y * gridDim.x + blockIdx.x;
  const int chunk = hw & 7, within = hw >> 3;
  const int chunk_rows = gridDim.y / CHM;
  const int cr = chunk % chunk_rows, cc = chunk / chunk_rows;
  const int mt = cr * CHM + within % CHM;
  const int nt = cc * CHN + within / CHM;
  const int m0 = mt * 256, n0 = nt * 128;
  const int tid = threadIdx.x, lane = tid & 63, w = tid >> 6;
  const int wm = w >> 1, wn = w & 1;
  const int frow = lane & 15, a4 = lane >> 4;
  const bf16* Ag = A + (size_t)m0 * KK;
  const bf16* Bg = Bt + (size_t)n0 * KK;
  f32x4 acc[4][4] = {};
  // prologue: tiles 0 and 1 in flight; complete 0, keep 1 flying
  stageN<4>(Ag, smA[0], w, lane);
  stageN<2>(Bg, smB[0], w, lane);
  stageN<4>(Ag + 64, smA[1], w, lane);
  stageN<2>(Bg + 64, smB[1], w, lane);
  asm volatile("s_waitcnt vmcnt(6)" ::: "memory");
  __builtin_amdgcn_s_barrier();
  for (int kt = 0; kt < NT; ++kt) {
    const bf16* At  = smA[kt % 3];
    const bf16* Btl = smB[kt % 3];
    bf16* As2 = smA[(kt + 2) % 3];
    bf16* Bs2 = smB[(kt + 2) % 3];
    const int kn2 = (kt + 2 < NT ? kt + 2 : kt) * 64;   // tail: harmless re-load
    bf16x8 af[2][2], bfr[4][2];
    // ---- phase 0: A rows 0-1 + all B frags; stage A(t+2)
#pragma unroll
    for (int mi = 0; mi < 2; ++mi)
#pragma unroll
      for (int kk = 0; kk < 2; ++kk)
        af[mi][kk] = rdfrag(At, wm * 64 + mi * 16 + frow, kk * 4 + a4);
#pragma unroll
    for (int ni = 0; ni < 4; ++ni)
#pragma unroll
      for (int kk = 0; kk < 2; ++kk)
        bfr[ni][kk] = rdfrag(Btl, wn * 64 + ni * 16 + frow, kk * 4 + a4);
    stageN<4>(Ag + kn2, As2, w, lane);
    PH_SYNC();
    __builtin_amdgcn_s_setprio(1);
#pragma unroll
    for (int mi = 0; mi < 2; ++mi)
#pragma unroll
      for (int ni = 0; ni < 4; ++ni)
#pragma unroll
        for (int kk = 0; kk < 2; ++kk)
          acc[mi][ni] = __builtin_amdgcn_mfma_f32_16x16x32_bf16(
              af[mi][kk], bfr[ni][kk], acc[mi][ni], 0, 0, 0);
    __builtin_amdgcn_s_setprio(0);
    __builtin_amdgcn_s_barrier();
    // ---- phase 1: A rows 2-3; stage B(t+2); counted vmcnt at boundary
#pragma unroll
    for (int mi = 0; mi < 2; ++mi)
#pragma unroll
      for (int kk = 0; kk < 2; ++kk)
        af[mi][kk] = rdfrag(At, wm * 64 + (2 + mi) * 16 + frow, kk * 4 + a4);
    stageN<2>(Bg + kn2, Bs2, w, lane);
    PH_SYNC();
    __builtin_amdgcn_s_setprio(1);
#pragma unroll
    for (int mi = 0; mi < 2; ++mi)
#pragma unroll
      for (int ni = 0; ni < 4; ++ni)
#pragma unroll
        for (int kk = 0; kk < 2; ++kk)
          acc[2 + mi][ni] = __builtin_amdgcn_mfma_f32_16x16x32_bf16(
              af[mi][kk], bfr[ni][kk], acc[2 + mi][ni], 0, 0, 0);
    __builtin_amdgcn_s_setprio(0);
    asm volatile("s_waitcnt vmcnt(6)" ::: "memory");   // t+1 complete, t+2 in flight
    __builtin_amdgcn_sched_barrier(0);
    __builtin_amdgcn_s_barrier();
  }
  // ---- epilogue
  if (MODE == 0) {
    const int z = n0 >> 11;
    const float* bias = (z == 0) ? biasq : (z == 1) ? biask : biasv;
    bf16* o = (z == 0) ? Qo : (z == 1) ? Ko : Vo;
    const float oscale = (z == 1) ? (float)(0.08838834764831845 * 1.4426950408889634) : 1.0f;
#pragma unroll
    for (int ni = 0; ni < 4; ++ni) {
      const int col = n0 + wn * 64 + ni * 16 + frow;
      const float bb_ = bias[col & 2047];
      const int h = (col >> 7) & 15, hd = col & (Hd - 1);
#pragma unroll
      for (int mi = 0; mi < 4; ++mi) {
#pragma unroll
        for (int r = 0; r < 4; ++r) {
          const int row = m0 + wm * 64 + mi * 16 + a4 * 4 + r;
          const int bb = row >> 11, ss = row & (Ssz - 1);
          o[(((size_t)bb * NHd + h) * Ssz + ss) * Hd + hd] = (bf16)((acc[mi][ni][r] + bb_) * oscale);
        }
      }
    }
  } else {
#pragma unroll
    for (int mi = 0; mi < 4; ++mi)
#pragma unroll
      for (int ni = 0; ni < 4; ++ni) {
        const int col = n0 + wn * 64 + ni * 16 + frow;
#pragma unroll
        for (int r = 0; r < 4; ++r) {
          const int row = m0 + wm * 64 + mi * 16 + a4 * 4 + r;
          Fo[(size_t)row * Hid + col] = acc[mi][ni][r];
        }
      }
  }
}

// ---------------- RoPE (neox) on Q and K in place --------------------------
__global__ void k_rope(bf16* __restrict__ Q, bf16* __restrict__ Kk, const int* __restrict__ pos) {
  const int idx = blockIdx.x * 256 + threadIdx.x;   // (bh, s, i) i fastest
  const int i = idx & 63;
  const int s = (idx >> 6) & (Ssz - 1);
  const int bh = idx >> 17;
  const int b = bh >> 4;
  const float p = (float)pos[b * Ssz + s];
  const float f = p * exp2f(-(float)i * 0.20762050593046014f); // log2(1e4)/64
  float sn, cs;
  sincosf(f, &sn, &cs);
  const size_t base = ((size_t)bh * Ssz + s) * Hd;
  float x1 = (float)Q[base + i], x2 = (float)Q[base + i + 64];
  Q[base + i]      = (bf16)(x1 * cs - x2 * sn);
  Q[base + i + 64] = (bf16)(x2 * cs + x1 * sn);
  x1 = (float)Kk[base + i]; x2 = (float)Kk[base + i + 64];
  Kk[base + i]      = (bf16)(x1 * cs - x2 * sn);
  Kk[base + i + 64] = (bf16)(x2 * cs + x1 * sn);
}

// ------------- causal flash attention, swapped-QK, 32x32x16 MFMA -----------
// T14 async-stage: K(t+1) gload_lds + V(t+1)->reg issued before compute(t);
// double-buffered K/V LDS; counted vmcnt(8) before the compute barrier.
__global__ __launch_bounds__(256, 2) void k_attn(const bf16* __restrict__ Qg,
                                                 const bf16* __restrict__ Kg,
                                                 const bf16* __restrict__ Vg,
                                                 bf16* __restrict__ AO) {
  const int bh = blockIdx.y;
  int qc = blockIdx.x;
  if (bh & 1) qc = 15 - qc;            // causal load balance across co-resident blocks
  const int tid = threadIdx.x, lane = tid & 63, w = tid >> 6;
  const int l31 = lane & 31, h = lane >> 5;
  __shared__ bf16 Ks[2][64 * 128];     // XOR-swizzled contents (16B granule by row&7)
  __shared__ bf16 Vt[2][128 * 72];     // V^T: [hd][key], pad 72, swz by (hd>>3)&7
  const size_t hbase = (size_t)bh * Ssz * Hd;
  const int q0 = qc * 128 + w * 32;    // wave's first query row
  bf16x8 qf[8];
  {
    const bf16* qp = Qg + hbase + (size_t)(q0 + l31) * Hd + h * 8;
#pragma unroll
    for (int c = 0; c < 8; c++) qf[c] = *(const bf16x8*)(qp + c * 16);
  }
  float m = -1e30f, lsum = 0.f;
  f32x16 o[4] = {};
  const int NT = 2 * (qc + 1);
  const int r4  = (tid >> 4) << 2;     // V staging: this thread's 4 keys
  const int hd0 = (tid & 15) << 3;     //   and 8 hd values
  bf16x8 vv[4];
  // ---- prologue: issue tile-0 V->reg then K->LDS
#pragma unroll
  for (int p = 0; p < 4; p++)
    vv[p] = *(const bf16x8*)(Vg + hbase + (size_t)(r4 + p) * Hd + hd0);
  __builtin_amdgcn_sched_barrier(0);
#pragma unroll
  for (int i = 0; i < 4; i++) {
    const int db  = (w * 4 + i) * 1024 + (lane << 4);
    const int row = db >> 8;
    const int cb  = (db & 255) ^ ((row & 7) << 4);
    gload_lds16(Kg + hbase + row * Hd + (cb >> 1), Ks[0] + (w * 4 + i) * 512);
  }
  for (int t = 0; t < NT; ++t) {
    const int kv0 = t * 64;
    const int cur = t & 1;
    // ---- V(t) regs ready (oldest 4 of <=8 outstanding); write V(t) -> LDS
    asm volatile("s_waitcnt vmcnt(4)" ::: "memory");
#pragma unroll
    for (int j = 0; j < 8; j++) {
      uint2 wv;
      wv.x = pkbf(vv[0][j], vv[1][j]);
      wv.y = pkbf(vv[2][j], vv[3][j]);
      const int hd = hd0 + j;
      const int cb = (r4 * 2) ^ (((hd >> 3) & 7) << 4);
      *(uint2*)((char*)(Vt[cur]) + hd * 144 + cb) = wv;
    }
    // ---- issue tile t+1 (redundant re-issue of t on last iter)
    const int tn = (t + 1 < NT) ? t + 1 : t;
    const size_t nb = (size_t)tn * 64;
#pragma unroll
    for (int p = 0; p < 4; p++)
      vv[p] = *(const bf16x8*)(Vg + hbase + (nb + r4 + p) * Hd + hd0);
    __builtin_amdgcn_sched_barrier(0);
#pragma unroll
    for (int i = 0; i < 4; i++) {
      const int db  = (w * 4 + i) * 1024 + (lane << 4);
      const int row = db >> 8;
      const int cb  = (db & 255) ^ ((row & 7) << 4);
      gload_lds16(Kg + hbase + (nb + row) * Hd + (cb >> 1), Ks[cur ^ 1] + (w * 4 + i) * 512);
    }
    // ---- K(t) in LDS (8 newest = t+1's loads stay in flight); V writes visible
    asm volatile("s_waitcnt vmcnt(8) lgkmcnt(0)" ::: "memory");
    __builtin_amdgcn_sched_barrier(0);
    __builtin_amdgcn_s_barrier();
    if (kv0 <= q0 + 31) {              // wave-uniform: skip fully-masked tiles
      const bf16* KsC = Ks[cur];
      const bf16* VtC = Vt[cur];
      f32x16 s0 = {}, s1 = {};
#pragma unroll
      for (int c = 0; c < 8; c++) {
        const int cb = (c * 32 + h * 16) ^ ((l31 & 7) << 4);
        bf16x8 k0 = *(const bf16x8*)((const char*)KsC + l31 * 256 + cb);
        bf16x8 k1 = *(const bf16x8*)((const char*)KsC + (32 + l31) * 256 + cb);
        s0 = __builtin_amdgcn_mfma_f32_32x32x16_bf16(k0, qf[c], s0, 0, 0, 0);
        s1 = __builtin_amdgcn_mfma_f32_32x32x16_bf16(k1, qf[c], s1, 0, 0, 0);
      }
      if (kv0 + 63 > q0) {
        const int qg = q0 + l31;
        const int kb = kv0 + 4 * h;
#pragma unroll
        for (int r = 0; r < 16; r++) {
          const int cr = (r & 3) + 8 * (r >> 2);
          if (kb + cr > qg)      s0[r] = -1e30f;
          if (kb + 32 + cr > qg) s1[r] = -1e30f;
        }
      }
      float tm = s0[0];
#pragma unroll
      for (int r = 1; r < 16; r++) tm = fmaxf(tm, s0[r]);
#pragma unroll
      for (int r = 0; r < 16; r++) tm = fmaxf(tm, s1[r]);
      tm = fmaxf(tm, __shfl_xor(tm, 32));
      if (!__all(tm - m <= 8.0f)) {    // defer-max (T13)
        const float mn = fmaxf(m, tm);
        const float rs = exp2f(m - mn);
        m = mn; lsum *= rs;
#pragma unroll
        for (int ct = 0; ct < 4; ct++)
#pragma unroll
          for (int r = 0; r < 16; r++) o[ct][r] *= rs;
      }
      float ps = 0.f;
#pragma unroll
      for (int r = 0; r < 16; r++) { s0[r] = exp2f(s0[r] - m); ps += s0[r]; }
#pragma unroll
      for (int r = 0; r < 16; r++) { s1[r] = exp2f(s1[r] - m); ps += s1[r]; }
      ps += __shfl_xor(ps, 32);
      lsum += ps;
      uint32_t gw[8][2];
#pragma unroll
      for (int g = 0; g < 4; g++) {
        gw[g][0]     = pkff(s0[4 * g], s0[4 * g + 1]);
        gw[g][1]     = pkff(s0[4 * g + 2], s0[4 * g + 3]);
        gw[4 + g][0] = pkff(s1[4 * g], s1[4 * g + 1]);
        gw[4 + g][1] = pkff(s1[4 * g + 2], s1[4 * g + 3]);
      }
#pragma unroll
      for (int kc = 0; kc < 4; kc++) {
        const uint32_t a0 = gw[2 * kc][0], a1 = gw[2 * kc][1];
        const uint32_t b0 = gw[2 * kc + 1][0], b1 = gw[2 * kc + 1][1];
        const uint32_t sd0 = h ? a0 : b0, sd1 = h ? a1 : b1;
        const uint32_t r0 = (uint32_t)__shfl_xor((int)sd0, 32);
        const uint32_t r1 = (uint32_t)__shfl_xor((int)sd1, 32);
        union { uint32_t u[4]; bf16x8 v; } pa;
        pa.u[0] = h ? r0 : a0; pa.u[1] = h ? r1 : a1;
        pa.u[2] = h ? b0 : r0; pa.u[3] = h ? b1 : r1;
#pragma unroll
        for (int ct = 0; ct < 4; ct++) {
          const int row = ct * 32 + l31;
          const int cb = (kc * 32 + h * 16) ^ (((row >> 3) & 7) << 4);
          bf16x8 vf = *(const bf16x8*)((const char*)VtC + row * 144 + cb);
          o[ct] = __builtin_amdgcn_mfma_f32_32x32x16_bf16(pa.v, vf, o[ct], 0, 0, 0);
        }
      }
    }
    __builtin_amdgcn_s_barrier();      // compute done before next tile's writes
  }
  const float linv = 1.0f / lsum;
  float li[16];
#pragma unroll
  for (int r = 0; r < 16; r++)
    li[r] = __shfl(linv, (r & 3) + 8 * (r >> 2) + 4 * h);
  const int b = bh >> 4, hh = bh & 15;
#pragma unroll
  for (int ct = 0; ct < 4; ct++) {
#pragma unroll
    for (int r = 0; r < 16; r++) {
      const int qrow = q0 + (r & 3) + 8 * (r >> 2) + 4 * h;
      AO[((size_t)b * Ssz + qrow) * Hid + hh * Hd + ct * 32 + l31] = (bf16)(o[ct][r] * li[r]);
    }
  }
}

extern "C" void kernel_launch(void* const* d_in, const int* in_sizes, int n_in,
                              void* d_out, int out_size, void* d_ws, size_t ws_size,
                              hipStream_t stream) {
  (void)in_sizes; (void)n_in; (void)out_size; (void)ws_size;
  const float* hidden   = (const float*)d_in[0];
  const int*   positions= (const int*)d_in[1];
  const float* wq = (const float*)d_in[2];
  const float* bq = (const float*)d_in[3];
  const float* wk = (const float*)d_in[4];
  const float* bk = (const float*)d_in[5];
  const float* wv = (const float*)d_in[6];
  const float* bv = (const float*)d_in[7];
  const float* wc = (const float*)d_in[8];
  float* out = (float*)d_out;

  char* ws = (char*)d_ws;
  bf16* WT  = (bf16*)ws;                                               // 4*Hid*Hid bf16 (q,k,v,c)
  bf16* Hbf = (bf16*)(ws + (size_t)4 * Hid * Hid * 2);                 // Mrows*Hid (reused as AO)
  bf16* Qb  = (bf16*)(ws + (size_t)4 * Hid * Hid * 2 + (size_t)Mrows * Hid * 2);
  bf16* Kb  = Qb + (size_t)Mrows * Hid;
  bf16* Vb  = Kb + (size_t)Mrows * Hid;

  k_cvt<<<dim3(Mrows * Hid / 4 / 256), dim3(256), 0, stream>>>(hidden, Hbf, Mrows * Hid / 4);
  k_wtrans<<<dim3(Hid / 32, Hid / 32, 4), dim3(32, 8), 0, stream>>>(wq, wk, wv, wc, WT);
  // fused QKV: N = 6144, grid 48x16 = 768 blocks; XCD chunks 8m x 12n
  k_gemm<0, 8, 12><<<dim3(48, 16), dim3(512), 0, stream>>>(
      Hbf, WT, bq, bk, bv, Qb, Kb, Vb, nullptr);
  k_rope<<<dim3(Bsz * NHd * Ssz * 64 / 256), dim3(256), 0, stream>>>(Qb, Kb, positions);
  k_attn<<<dim3(16, Bsz * NHd), dim3(256), 0, stream>>>(Qb, Kb, Vb, Hbf /*AO*/);
  // output projection: grid 16x16 = 256 blocks; XCD chunks 4m x 8n
  k_gemm<1, 4, 8><<<dim3(16, 16), dim3(512), 0, stream>>>(
      Hbf, WT + (size_t)3 * Hid * Hid, nullptr, nullptr, nullptr,
      nullptr, nullptr, nullptr, out);
}